// Round 8
// baseline (6907.816 us; speedup 1.0000x reference)
//
#include <hip/hip_runtime.h>
#include <cmath>

// ---------------- numerics model (F-c): ----------------
// Every tensor is f32; every op is computed with f64 internals and ONE
// f32 rounding at its output:
//   h1 = fl32( selu_f64( fl32( conv_f64(x, w1) ) ) )        (bias = 0)
//   h2 = fl32( selu_f64( fl32( conv_f64(h1, w2) ) ) )
//   z  = fl32( conv_f64(h2, w3) )
//   S  = fl32( sum_f64 z^2 ), G_n = fl32( dot_f64(z, e_n) ),
//   E_n = fl32( sum_f64 e_n^2 )
//   d_n = (S - 2*G_n) + E_n     [plain f32 two-op combine]
//   idx = argmin_n d_n (strict <, first index);  q = z + (e - z)  [f32 ops]
// Decoder: plain f32 (recon has passed in all 6 prior runs).
#define BATCH 32

static const size_t N_H2 = 32u*32*120*120;   // 14,745,600 (f32 now)
static const size_t N_Q  = 32u*64*116*116;
static const size_t RECON_FLOATS = 32u*3*128*128;

// ---- workspace byte layout ----
static const size_t OFF_W1D  = 0;                         // 2400  f64
static const size_t OFF_W2D  = OFF_W1D + 2400*8;          // 25600 f64
static const size_t OFF_W3D  = OFF_W2D + 25600*8;         // 51200 f64
static const size_t OFF_W4F  = OFF_W3D + 51200*8;         // 51200 f32
static const size_t OFF_W5F  = OFF_W4F + 51200*4;         // 25600 f32
static const size_t OFF_W6F  = OFF_W5F + 25600*4;         // 2400  f32
static const size_t OFF_EMBD = (OFF_W6F + 2400*4 + 255) & ~(size_t)255; // 512*64 f64
static const size_t OFF_EN32 = OFF_EMBD + 32768*8;        // 512 f32
static const size_t OFF_H2F  = (OFF_EN32 + 512*4 + 255) & ~(size_t)255; // h2 f32, 59MB
static const size_t OFF_QF   = OFF_H2F + N_H2*4;          // Q f32, 110MB
// decoder aliases: D1 -> OFF_H2F (h2 dead), D2 -> OFF_QF (Q dead after convT1)

// ---------------- helpers ----------------
__device__ inline double selu64(double r) {
    double neg = 1.6732632423543772848170429916717 * expm1(r);
    return 1.0507009873554804934193349852946 * (r > 0. ? r : neg);
}
__device__ inline float selu32(float r) {
    float neg = 1.6732632423543772848170429916717f * expm1f(r);
    return 1.0507009873554804934193349852946f * (r > 0.f ? r : neg);
}

// ---------------- weight re-layout: -> [ky][kx][ic][oc] ----------------
template<typename TOUT>
__global__ void wtrans_k(const float* __restrict__ w, TOUT* __restrict__ wt,
                         int IC, int OC, int trans) {
    int i = blockIdx.x * 256 + threadIdx.x;
    int tot = IC * OC * 25;
    if (i >= tot) return;
    int o  = i % OC;
    int t  = i / OC;
    int ic = t % IC;  t /= IC;
    int kx = t % 5;
    int ky = t / 5;
    float v;
    if (trans) v = w[(((ic * OC) + o) * 5 + ky) * 5 + kx];   // IOHW
    else       v = w[(((o * IC) + ic) * 5 + ky) * 5 + kx];   // OIHW
    wt[i] = (TOUT)v;
}

// ---------------- codebook: f64 table + E_n = fl32(f64 sum e^2) -------------
__global__ void prep_embd(const float* __restrict__ emb, double* __restrict__ embd,
                          float* __restrict__ En32) {
    int n = blockIdx.x * 256 + threadIdx.x;
    if (n >= 512) return;
    double s = 0.;
    for (int c = 0; c < 64; ++c) {
        double e = (double)emb[n * 64 + c];
        embd[n * 64 + c] = e;
        s = fma(e, e, s);
    }
    En32[n] = (float)s;
}

// ---------------- fused conv1+conv2: f64 internals, f32 boundaries ----------
__global__ __launch_bounds__(256)
void enc12_k(const float* __restrict__ x, const double* __restrict__ w1,
             const float* __restrict__ b1, const double* __restrict__ w2,
             const float* __restrict__ b2, float* __restrict__ h2out) {
    __shared__ float xs[3][24][24];     // x tile (f32 exact)
    __shared__ float h1s[8][20][20];    // h1 chunk, f32 boundary
    const int tid = threadIdx.x;
    const int tx = tid & 15, ty = tid >> 4;
    const int ox0 = blockIdx.x * 16, oy0 = blockIdx.y * 16;
    const int b = blockIdx.z;

    for (int i = tid; i < 3 * 576; i += 256) {
        int ic = i / 576;
        int r  = i - ic * 576;
        int sy = r / 24, sx = r - sy * 24;
        int gy = oy0 + sy, gx = ox0 + sx;
        float v = 0.f;
        if (gy < 128 && gx < 128)
            v = x[((size_t)(b * 3 + ic) * 128 + gy) * 128 + gx];
        xs[ic][sy][sx] = v;
    }

    double acc2[32];
#pragma unroll
    for (int o = 0; o < 32; ++o) acc2[o] = (double)b2[o];

    for (int cc = 0; cc < 4; ++cc) {
        __syncthreads();
        for (int j = tid; j < 8 * 400; j += 256) {
            int ch = j / 400;
            int r  = j - ch * 400;
            int sy = r / 20, sx = r - sy * 20;
            int oc1 = cc * 8 + ch;
            int gy = oy0 + sy, gx = ox0 + sx;
            float hv = 0.f;
            if (gy < 124 && gx < 124) {
                double a = (double)b1[oc1];
#pragma unroll
                for (int ky = 0; ky < 5; ++ky)
#pragma unroll
                    for (int kx = 0; kx < 5; ++kx)
#pragma unroll
                        for (int ic = 0; ic < 3; ++ic)
                            a = fma((double)xs[ic][sy + ky][sx + kx],
                                    w1[((size_t)(ky * 5 + kx) * 3 + ic) * 32 + oc1], a);
                float c32 = (float)a;                 // conv op -> f32 boundary
                hv = (float)selu64((double)c32);      // selu op -> f32 boundary
            }
            h1s[ch][sy][sx] = hv;
        }
        __syncthreads();
        for (int icl = 0; icl < 8; ++icl) {
            int gic = cc * 8 + icl;
#pragma unroll
            for (int ky = 0; ky < 5; ++ky)
#pragma unroll
                for (int kx = 0; kx < 5; ++kx) {
                    double v = (double)h1s[icl][ty + ky][tx + kx];
                    const double* wp = w2 + ((size_t)(ky * 5 + kx) * 32 + gic) * 32;
#pragma unroll
                    for (int o = 0; o < 32; ++o)
                        acc2[o] = fma(v, wp[o], acc2[o]);
                }
        }
    }

    const int y2 = oy0 + ty, x2 = ox0 + tx;
    if (y2 < 120 && x2 < 120) {
#pragma unroll
        for (int o = 0; o < 32; ++o) {
            float c32 = (float)acc2[o];               // conv -> f32
            h2out[((size_t)(b * 32 + o) * 120 + y2) * 120 + x2]
                = (float)selu64((double)c32);         // selu -> f32
        }
    }
}

// ------- fused conv3 (f64 acc -> f32 z) + VQ (f64-internal S,G; f32 d) ------
__global__ __launch_bounds__(256)
void conv3vq_k(const float* __restrict__ h2, const double* __restrict__ wt,
               const float* __restrict__ bias, const double* __restrict__ embd,
               const float* __restrict__ En32, const float* __restrict__ embf,
               float* __restrict__ q, float* __restrict__ idxo) {
    __shared__ float slds[16][20][20];
    const int tid = threadIdx.x;
    const int tx = tid & 15, ty = tid >> 4;
    const int ox0 = blockIdx.x * 16, oy0 = blockIdx.y * 16;
    const int b = blockIdx.z;

    double acc[64];
#pragma unroll
    for (int o = 0; o < 64; ++o) acc[o] = (double)bias[o];

    for (int cc = 0; cc < 2; ++cc) {
        __syncthreads();
        for (int i = tid; i < 16 * 400; i += 256) {
            int ic = i / 400;
            int r  = i - ic * 400;
            int sy = r / 20, sx = r - sy * 20;
            int gy = oy0 + sy, gx = ox0 + sx;
            float v = 0.f;
            if (gy < 120 && gx < 120)
                v = h2[((size_t)(b * 32 + cc * 16 + ic) * 120 + gy) * 120 + gx];
            slds[ic][sy][sx] = v;
        }
        __syncthreads();

        for (int ic = 0; ic < 16; ++ic) {
            int gic = cc * 16 + ic;
#pragma unroll
            for (int ky = 0; ky < 5; ++ky)
#pragma unroll
                for (int kx = 0; kx < 5; ++kx) {
                    double v = (double)slds[ic][ty + ky][tx + kx];
                    const double* wp = wt + ((size_t)(ky * 5 + kx) * 32 + gic) * 64;
#pragma unroll
                    for (int o = 0; o < 64; ++o)
                        acc[o] = fma(v, wp[o], acc[o]);
                }
        }
    }

    const int oy = oy0 + ty, ox = ox0 + tx;
    if (oy >= 116 || ox >= 116) return;

    // z: f32 boundary
    float z32[64];
#pragma unroll
    for (int c = 0; c < 64; ++c) z32[c] = (float)acc[c];

    // S = fl32( f64 sum z^2 )
    double Sd = 0.;
#pragma unroll
    for (int c = 0; c < 64; ++c) {
        double zv = (double)z32[c];
        Sd = fma(zv, zv, Sd);
    }
    const float S32 = (float)Sd;

    // argmin over d_n = (S32 - 2*G32_n) + E32_n, G32 = fl32(f64 dot)
    float bestd = __builtin_huge_valf();
    int best = 0;
    for (int n = 0; n < 512; n += 4) {
        const double* e0 = embd + (size_t)n * 64;
        const double* e1 = e0 + 64;
        const double* e2 = e0 + 128;
        const double* e3 = e0 + 192;
        double G0 = 0., G1 = 0., G2 = 0., G3 = 0.;
#pragma unroll
        for (int c = 0; c < 64; ++c) {
            double zv = (double)z32[c];
            G0 = fma(zv, e0[c], G0);
            G1 = fma(zv, e1[c], G1);
            G2 = fma(zv, e2[c], G2);
            G3 = fma(zv, e3[c], G3);
        }
        float g0 = (float)G0, g1 = (float)G1, g2 = (float)G2, g3 = (float)G3;
        float d0 = (S32 - 2.0f * g0) + En32[n];
        float d1 = (S32 - 2.0f * g1) + En32[n + 1];
        float d2 = (S32 - 2.0f * g2) + En32[n + 2];
        float d3 = (S32 - 2.0f * g3) + En32[n + 3];
        if (d0 < bestd) { bestd = d0; best = n; }
        if (d1 < bestd) { bestd = d1; best = n + 1; }
        if (d2 < bestd) { bestd = d2; best = n + 2; }
        if (d3 < bestd) { bestd = d3; best = n + 3; }
    }

    const float* e = embf + (size_t)best * 64;
#pragma unroll
    for (int c = 0; c < 64; ++c) {
        float zv = z32[c];
        float diff = e[c] - zv;
        q[((size_t)(b * 64 + c) * 116 + oy) * 116 + ox] = zv + diff;
    }
    idxo[((size_t)b * 116 + oy) * 116 + ox] = (float)best;
}

// ---------------- decoder direct convT kernel (fp32) ----------------
template<int IC, int ICB, int OC, bool DOSELU>
__global__ __launch_bounds__(256)
void deconv5_k(const float* __restrict__ in, const float* __restrict__ wt,
               const float* __restrict__ bias, float* __restrict__ out,
               int Hin, int Win, int Hout, int Wout) {
    constexpr int NCH = IC / ICB;
    __shared__ float slds[ICB][20][20];
    const int tid = threadIdx.x;
    const int tx = tid & 15, ty = tid >> 4;
    const int ox0 = blockIdx.x * 16, oy0 = blockIdx.y * 16;
    const int b = blockIdx.z;

    float acc[OC];
#pragma unroll
    for (int o = 0; o < OC; ++o) acc[o] = bias[o];

    for (int cc = 0; cc < NCH; ++cc) {
        __syncthreads();
        for (int i = tid; i < ICB * 400; i += 256) {
            int ic = i / 400;
            int r  = i - ic * 400;
            int sy = r / 20, sx = r - sy * 20;
            int gy = oy0 - 4 + sy;
            int gx = ox0 - 4 + sx;
            float v = 0.f;
            if (gy >= 0 && gy < Hin && gx >= 0 && gx < Win)
                v = in[((size_t)(b * IC + cc * ICB + ic) * Hin + gy) * Win + gx];
            slds[ic][sy][sx] = v;
        }
        __syncthreads();

        for (int ic = 0; ic < ICB; ++ic) {
            int gic = cc * ICB + ic;
#pragma unroll
            for (int ky = 0; ky < 5; ++ky)
#pragma unroll
                for (int kx = 0; kx < 5; ++kx) {
                    float v = slds[ic][ty + ky][tx + kx];
                    const float* wp = wt + ((size_t)(ky * 5 + kx) * IC + gic) * OC;
#pragma unroll
                    for (int o = 0; o < OC; ++o)
                        acc[o] = fmaf(v, wp[o], acc[o]);
                }
        }
    }

    const int oy = oy0 + ty, ox = ox0 + tx;
    if (oy < Hout && ox < Wout) {
#pragma unroll
        for (int o = 0; o < OC; ++o) {
            float r = acc[o];
            if (DOSELU) r = selu32(r);
            out[((size_t)(b * OC + o) * Hout + oy) * Wout + ox] = r;
        }
    }
}

// ---------------- launcher ----------------
extern "C" void kernel_launch(void* const* d_in, const int* in_sizes, int n_in,
                              void* d_out, int out_size, void* d_ws, size_t ws_size,
                              hipStream_t stream) {
    const float* x   = (const float*)d_in[0];
    const float* ew1 = (const float*)d_in[1];
    const float* eb1 = (const float*)d_in[2];
    const float* ew2 = (const float*)d_in[3];
    const float* eb2 = (const float*)d_in[4];
    const float* ew3 = (const float*)d_in[5];
    const float* eb3 = (const float*)d_in[6];
    const float* dw1 = (const float*)d_in[7];
    const float* db1 = (const float*)d_in[8];
    const float* dw2 = (const float*)d_in[9];
    const float* db2 = (const float*)d_in[10];
    const float* dw3 = (const float*)d_in[11];
    const float* db3 = (const float*)d_in[12];
    const float* emb = (const float*)d_in[13];

    char* base = (char*)d_ws;
    double* W1D  = (double*)(base + OFF_W1D);
    double* W2D  = (double*)(base + OFF_W2D);
    double* W3D  = (double*)(base + OFF_W3D);
    float*  W4F  = (float*) (base + OFF_W4F);
    float*  W5F  = (float*) (base + OFF_W5F);
    float*  W6F  = (float*) (base + OFF_W6F);
    double* EMBD = (double*)(base + OFF_EMBD);
    float*  EN32 = (float*) (base + OFF_EN32);
    float*  H2F  = (float*) (base + OFF_H2F);
    float*  QF   = (float*) (base + OFF_QF);
    float*  D1   = (float*) (base + OFF_H2F);   // h2 dead by then
    float*  D2   = (float*) (base + OFF_QF);    // Q dead after convT1

    float* recon = (float*)d_out;
    float* idxo  = (float*)d_out + RECON_FLOATS;

    wtrans_k<double><<<dim3((2400  + 255) / 256), 256, 0, stream>>>(ew1, W1D,  3, 32, 0);
    wtrans_k<double><<<dim3((25600 + 255) / 256), 256, 0, stream>>>(ew2, W2D, 32, 32, 0);
    wtrans_k<double><<<dim3((51200 + 255) / 256), 256, 0, stream>>>(ew3, W3D, 32, 64, 0);
    wtrans_k<float ><<<dim3((51200 + 255) / 256), 256, 0, stream>>>(dw1, W4F, 64, 32, 1);
    wtrans_k<float ><<<dim3((25600 + 255) / 256), 256, 0, stream>>>(dw2, W5F, 32, 32, 1);
    wtrans_k<float ><<<dim3((2400  + 255) / 256), 256, 0, stream>>>(dw3, W6F, 32,  3, 1);
    prep_embd<<<dim3(2), 256, 0, stream>>>(emb, EMBD, EN32);

    dim3 grd(8, 8, BATCH);

    enc12_k<<<grd, 256, 0, stream>>>(x, W1D, eb1, W2D, eb2, H2F);
    conv3vq_k<<<grd, 256, 0, stream>>>(H2F, W3D, eb3, EMBD, EN32, emb, QF, idxo);

    deconv5_k<64, 32, 32, true ><<<grd, 256, 0, stream>>>(QF, W4F, db1, D1, 116, 116, 120, 120);
    deconv5_k<32, 32, 32, true ><<<grd, 256, 0, stream>>>(D1, W5F, db2, D2, 120, 120, 124, 124);
    deconv5_k<32, 32, 3,  false><<<grd, 256, 0, stream>>>(D2, W6F, db3, recon, 124, 124, 128, 128);
}